// Round 1
// baseline (1107.235 us; speedup 1.0000x reference)
//
#include <hip/hip_runtime.h>

#define Bq 2
#define Hh 8
#define Ss 512
#define HD 64
#define DIM 512

// ---------------- generic batched tiled fp32 GEMM ----------------
// C[m,n] = alpha * sum_k A[m,k] * (TB ? B[n,k] : B[k,n])  (+ bias[n]) (+ diag if m==n)
// All of M,N multiples of 64; K multiple of 16. Batch z = b*nh + h; each operand
// gets base + b*sb + h*sh.
template<bool TB>
__global__ __launch_bounds__(256) void gemm_k(
    const float* __restrict__ A, long a_sb, long a_sh, int lda,
    const float* __restrict__ Bp, long b_sb, long b_sh, int ldb,
    const float* __restrict__ bias, long bias_sb, long bias_sh,
    float* __restrict__ C, long c_sb, long c_sh, int ldc,
    int M, int N, int K, float alpha, float diag, int nh)
{
    int z = blockIdx.z;
    int bb = z / nh, hh = z % nh;
    A += (long)bb * a_sb + (long)hh * a_sh;
    Bp += (long)bb * b_sb + (long)hh * b_sh;
    C += (long)bb * c_sb + (long)hh * c_sh;
    if (bias) bias += (long)bb * bias_sb + (long)hh * bias_sh;

    __shared__ float As[16][68];   // [kk][m], pad 68 -> 2-way max on store, free
    __shared__ float Bs[16][68];   // [kk][n]

    int tid = threadIdx.x;
    int tx = tid & 15, ty = tid >> 4;
    int row0 = blockIdx.y * 64, col0 = blockIdx.x * 64;

    float acc[4][4] = {};

    for (int k0 = 0; k0 < K; k0 += 16) {
#pragma unroll
        for (int r = 0; r < 4; ++r) {
            int idx = r * 256 + tid;
            int m = idx >> 4, kk = idx & 15;
            As[kk][m] = A[(long)(row0 + m) * lda + (k0 + kk)];
        }
#pragma unroll
        for (int r = 0; r < 4; ++r) {
            int idx = r * 256 + tid;
            if (TB) {
                int n = idx >> 4, kk = idx & 15;
                Bs[kk][n] = Bp[(long)(col0 + n) * ldb + (k0 + kk)];
            } else {
                int kk = idx >> 6, n = idx & 63;
                Bs[kk][n] = Bp[(long)(k0 + kk) * ldb + (col0 + n)];
            }
        }
        __syncthreads();
#pragma unroll
        for (int kk = 0; kk < 16; ++kk) {
            float4 av = *(const float4*)&As[kk][ty * 4];
            float4 bv = *(const float4*)&Bs[kk][tx * 4];
            float a[4] = {av.x, av.y, av.z, av.w};
            float b[4] = {bv.x, bv.y, bv.z, bv.w};
#pragma unroll
            for (int i = 0; i < 4; ++i)
#pragma unroll
                for (int j = 0; j < 4; ++j)
                    acc[i][j] += a[i] * b[j];
        }
        __syncthreads();
    }

#pragma unroll
    for (int i = 0; i < 4; ++i) {
        int m = row0 + ty * 4 + i;
#pragma unroll
        for (int j = 0; j < 4; ++j) {
            int n = col0 + tx * 4 + j;
            float v = alpha * acc[i][j];
            if (bias) v += bias[n];
            if (diag != 0.0f && m == n) v += diag;
            C[(long)m * ldc + n] = v;
        }
    }
}

// ---------------- W = exp(-L1(q_i,k_j)/4) * causal ----------------
// blockIdx: x = j-tile(32), y = i-tile(32), z = b*H+h. qkv layout [B,S,3*DIM].
__global__ __launch_bounds__(256) void w_kernel(const float* __restrict__ qkv,
                                                float* __restrict__ W)
{
    int z = blockIdx.z;
    int b = z / Hh, h = z % Hh;
    int i0 = blockIdx.y * 32, j0 = blockIdx.x * 32;
    int tid = threadIdx.x;
    int j = tid & 31;        // col within tile (fastest across lanes -> coalesced writes)
    int iB = tid >> 5;       // 0..7
    float* Wb = W + (long)z * Ss * Ss;

    if (j0 > i0 + 31) {      // fully masked tile: just write zeros
#pragma unroll
        for (int p = 0; p < 4; ++p) {
            int gi = i0 + iB + 8 * p, gj = j0 + j;
            Wb[(long)gi * Ss + gj] = 0.0f;
        }
        return;
    }

    __shared__ float qs[32][65];   // pad 65 -> conflict-free for ks reads
    __shared__ float ks[32][65];
    const float* qb = qkv + (long)b * Ss * (3 * DIM) + h * HD;   // q(i,d) = qb[i*1536+d]
    const float* kb = qb + DIM;                                  // k(j,d)
#pragma unroll
    for (int r = 0; r < 8; ++r) {
        int idx = r * 256 + tid;
        int row = idx >> 6, d = idx & 63;
        qs[row][d] = qb[(long)(i0 + row) * (3 * DIM) + d];
        ks[row][d] = kb[(long)(j0 + row) * (3 * DIM) + d];
    }
    __syncthreads();

#pragma unroll
    for (int p = 0; p < 4; ++p) {
        int i = iB + 8 * p;
        float sum = 0.0f;
#pragma unroll
        for (int d = 0; d < 64; ++d)
            sum += fabsf(qs[i][d] - ks[j][d]);
        int gi = i0 + i, gj = j0 + j;
        float w = (gj <= gi) ? expf(-sum * 0.25f) : 0.0f;
        Wb[(long)gi * Ss + gj] = w;
    }
}

// ---------------- batched 512x512 transpose ----------------
__global__ __launch_bounds__(256) void transpose_k(const float* __restrict__ W,
                                                   float* __restrict__ Wt)
{
    __shared__ float t[32][33];
    int z = blockIdx.z;
    const float* Wb = W + (long)z * Ss * Ss;
    float* Wtb = Wt + (long)z * Ss * Ss;
    int x0 = blockIdx.x * 32, y0 = blockIdx.y * 32;
    int tid = threadIdx.x;
    int lx = tid & 31, ly = tid >> 5;   // ly 0..7
#pragma unroll
    for (int r = 0; r < 4; ++r)
        t[ly + 8 * r][lx] = Wb[(long)(y0 + ly + 8 * r) * Ss + x0 + lx];
    __syncthreads();
#pragma unroll
    for (int r = 0; r < 4; ++r)
        Wtb[(long)(x0 + ly + 8 * r) * Ss + y0 + lx] = t[lx][ly + 8 * r];
}

// ---------------- scale = 1/(max colsum * max rowsum) per batch-head ----------------
__global__ __launch_bounds__(512) void norms_k(const float* __restrict__ W,
                                               const float* __restrict__ Wt,
                                               float* __restrict__ scale)
{
    int z = blockIdx.x;
    int j = threadIdx.x;
    const float* Wb = W + (long)z * Ss * Ss;
    const float* Wtb = Wt + (long)z * Ss * Ss;
    float cs = 0.0f, rs = 0.0f;
    for (int i = 0; i < Ss; ++i) {
        cs += Wb[(long)i * Ss + j];    // column sums of W  -> n1
        rs += Wtb[(long)i * Ss + j];   // column sums of Wt = row sums of W -> ninf
    }
    __shared__ float sA[512], sB[512];
    sA[j] = cs; sB[j] = rs;
    __syncthreads();
    for (int off = 256; off > 0; off >>= 1) {
        if (j < off) {
            sA[j] = fmaxf(sA[j], sA[j + off]);
            sB[j] = fmaxf(sB[j], sB[j + off]);
        }
        __syncthreads();
    }
    if (j == 0) scale[z] = 1.0f / (sA[0] * sB[0]);
}

// ---------------- X0 = Wt * scale ----------------
__global__ __launch_bounds__(256) void x0_k(const float* __restrict__ Wt,
                                            const float* __restrict__ scale,
                                            float* __restrict__ X)
{
    int z = blockIdx.z;
    long idx = (long)blockIdx.x * 256 + threadIdx.x;
    float s = scale[z];
    X[(long)z * Ss * Ss + idx] = Wt[(long)z * Ss * Ss + idx] * s;
}

// ---------------- per (h,j) sum / sumsq over (b,i) ----------------
__global__ __launch_bounds__(512) void stats_k(const float* __restrict__ W,
                                               float* __restrict__ ssum,
                                               float* __restrict__ ssq)
{
    int h = blockIdx.x, c = blockIdx.y, j = threadIdx.x;
    float s = 0.0f, q = 0.0f;
    for (int r = 0; r < 64; ++r) {
        int gr = c * 64 + r;            // over (b,i): 0..1023
        int b = gr >> 9, i = gr & 511;
        float v = W[(((long)b * Hh + h) * Ss + i) * Ss + j];
        s += v; q += v * v;
    }
    atomicAdd(&ssum[h * Ss + j], s);
    atomicAdd(&ssq[h * Ss + j], q);
}

__global__ __launch_bounds__(512) void statsfin_k(const float* __restrict__ ssum,
                                                  const float* __restrict__ ssq,
                                                  float* __restrict__ mu_is,
                                                  float* __restrict__ inv_sig)
{
    int h = blockIdx.x, j = threadIdx.x;
    float s = ssum[h * Ss + j], q = ssq[h * Ss + j];
    const float N = (float)(Bq * Ss);
    float mu = s / N;
    float var = (q - s * s / N) / (N - 1.0f);   // unbiased, ddof=1
    float is = 1.0f / sqrtf(var + 1e-5f);
    inv_sig[h * Ss + j] = is;
    mu_is[h * Ss + j] = mu * is;
}

// ---------------- c2s[j,d] = inv_sig[j]*ctx2[j,d] (in place); negoffs[d] = -sum_j mu_is[j]*ctx2[j,d]
__global__ __launch_bounds__(64) void scalec_k(const float* __restrict__ mu_is,
                                               const float* __restrict__ inv_sig,
                                               float* __restrict__ ctx2,
                                               float* __restrict__ negoffs)
{
    int z = blockIdx.x;
    int h = z % Hh;
    int d = threadIdx.x;
    float* c = ctx2 + (long)z * Ss * HD;
    float off = 0.0f;
    for (int j = 0; j < Ss; ++j) {
        float v = c[(long)j * HD + d];
        off += mu_is[h * Ss + j] * v;
        c[(long)j * HD + d] = inv_sig[h * Ss + j] * v;
    }
    negoffs[z * HD + d] = -off;
}

// ---------------- ga [B,H,S,HD] -> gat [B,S,H*HD] ----------------
__global__ __launch_bounds__(256) void permute_k(const float* __restrict__ ga,
                                                 float* __restrict__ gat)
{
    long idx = (long)blockIdx.x * 256 + threadIdx.x;   // over B*S*DIM
    int d = idx & 63;
    long t = idx >> 6;
    int h = t & 7; t >>= 3;
    int s = t & 511;
    int b = (int)(t >> 9);
    gat[idx] = ga[(((long)b * Hh + h) * Ss + s) * (long)HD + d];
}

extern "C" void kernel_launch(void* const* d_in, const int* in_sizes, int n_in,
                              void* d_out, int out_size, void* d_ws, size_t ws_size,
                              hipStream_t stream)
{
    const float* x      = (const float*)d_in[0];
    const float* qkv_w  = (const float*)d_in[1];
    const float* qkv_b  = (const float*)d_in[2];
    const float* proj_w = (const float*)d_in[3];
    const float* proj_b = (const float*)d_in[4];
    float* out = (float*)d_out;
    float* ws  = (float*)d_ws;

    const long SS = (long)Ss * Ss;             // 262144
    const long BH = (long)Bq * Hh;             // 16
    long o = 0;
    float* qkv  = ws + o; o += (long)Bq * Ss * 3 * DIM;  // 1.57M floats
    float* W    = ws + o; o += BH * SS;                  // 4.19M
    float* Wt   = ws + o; o += BH * SS;
    float* Xa   = ws + o; o += BH * SS;
    float* Xb   = ws + o; o += BH * SS;
    float* T    = ws + o; o += BH * SS;
    float* ctx  = ws + o; o += BH * Ss * HD;             // 1.05M
    float* ctx2 = ws + o; o += BH * Ss * HD;
    float* scale   = ws + o; o += 16;
    float* ssum    = ws + o; o += Hh * Ss;               // ssum+ssq contiguous (one memset)
    float* ssq     = ws + o; o += Hh * Ss;
    float* mu_is   = ws + o; o += Hh * Ss;
    float* inv_sig = ws + o; o += Hh * Ss;
    float* negoffs = ws + o; o += BH * HD;
    float* ga  = ctx;   // ctx dead after ctx2 is computed
    float* gat = T;     // T dead after NS loop

    dim3 blk(256);
    const long sW = Hh * SS;     // batch-b stride for [B,H,S,S] tensors
    const long sCt = (long)Hh * Ss * HD;

    // 1. qkv = x @ qkv_w^T + qkv_b     [1024,1536]
    gemm_k<true><<<dim3(1536 / 64, 1024 / 64, 1), blk, 0, stream>>>(
        x, 0, 0, DIM, qkv_w, 0, 0, DIM, qkv_b, 0, 0,
        qkv, 0, 0, 3 * DIM, Bq * Ss, 3 * DIM, DIM, 1.0f, 0.0f, 1);

    // 2. W = exp(-L1/4) * tril
    w_kernel<<<dim3(16, 16, 16), blk, 0, stream>>>(qkv, W);

    // 3. Wt = W^T (per batch-head)
    transpose_k<<<dim3(16, 16, 16), blk, 0, stream>>>(W, Wt);

    // 4. scale = 1/(n1*ninf)
    norms_k<<<dim3(16), dim3(512), 0, stream>>>(W, Wt, scale);

    // 5. X0 = Wt * scale
    x0_k<<<dim3(SS / 256, 1, 16), blk, 0, stream>>>(Wt, scale, Xa);

    // 6. Newton-Schulz: X <- X (2I - W X), 5 iters
    float* Xc = Xa; float* Xn = Xb;
    for (int it = 0; it < 5; ++it) {
        gemm_k<false><<<dim3(8, 8, 16), blk, 0, stream>>>(
            W, sW, SS, Ss, Xc, sW, SS, Ss, nullptr, 0, 0,
            T, sW, SS, Ss, Ss, Ss, Ss, -1.0f, 2.0f, Hh);
        gemm_k<false><<<dim3(8, 8, 16), blk, 0, stream>>>(
            Xc, sW, SS, Ss, T, sW, SS, Ss, nullptr, 0, 0,
            Xn, sW, SS, Ss, Ss, Ss, Ss, 1.0f, 0.0f, Hh);
        float* tmp = Xc; Xc = Xn; Xn = tmp;
    }
    // final inverse approx in Xc

    // 7. whitening stats over (b,i) per (h,j)
    hipMemsetAsync(ssum, 0, 2 * Hh * Ss * sizeof(float), stream);
    stats_k<<<dim3(Hh, 16), dim3(512), 0, stream>>>(W, ssum, ssq);
    statsfin_k<<<dim3(Hh), dim3(512), 0, stream>>>(ssum, ssq, mu_is, inv_sig);

    // 8. ctx = W^T @ v   (v read straight out of qkv: base +2*DIM, ldb=1536)
    gemm_k<false><<<dim3(1, 8, 16), blk, 0, stream>>>(
        Wt, sW, SS, Ss,
        qkv + 2 * DIM, (long)Ss * 3 * DIM, (long)HD, 3 * DIM,
        nullptr, 0, 0,
        ctx, sCt, (long)Ss * HD, HD, Ss, HD, Ss, 1.0f, 0.0f, Hh);

    // 9. ctx2 = W_inv @ ctx
    gemm_k<false><<<dim3(1, 8, 16), blk, 0, stream>>>(
        Xc, sW, SS, Ss, ctx, sCt, (long)Ss * HD, HD, nullptr, 0, 0,
        ctx2, sCt, (long)Ss * HD, HD, Ss, HD, Ss, 1.0f, 0.0f, Hh);

    // 10. fold whitening into ctx2 + column offsets
    scalec_k<<<dim3(16), dim3(64), 0, stream>>>(mu_is, inv_sig, ctx2, negoffs);

    // 11. ga = W @ ctx2_scaled + negoffs   (== W_norm @ ctx2)
    gemm_k<false><<<dim3(1, 8, 16), blk, 0, stream>>>(
        W, sW, SS, Ss, ctx2, sCt, (long)Ss * HD, HD,
        negoffs, (long)Hh * HD, (long)HD,
        ga, sCt, (long)Ss * HD, HD, Ss, HD, Ss, 1.0f, 0.0f, Hh);

    // 12. permute [B,H,S,HD] -> [B,S,DIM]
    permute_k<<<dim3((Bq * Ss * DIM) / 256), blk, 0, stream>>>(ga, gat);

    // 13. out = gat @ proj_w^T + proj_b
    gemm_k<true><<<dim3(512 / 64, 1024 / 64, 1), blk, 0, stream>>>(
        gat, 0, 0, DIM, proj_w, 0, 0, DIM, proj_b, 0, 0,
        out, 0, 0, DIM, Bq * Ss, DIM, DIM, 1.0f, 0.0f, 1);
}

// Round 3
// 786.716 us; speedup vs baseline: 1.4074x; 1.4074x over previous
//
#include <hip/hip_runtime.h>

#define Bq 2
#define Hh 8
#define Ss 512
#define HD 64
#define DIM 512

using bf16x8s = __attribute__((ext_vector_type(8))) short;
using f32x4   = __attribute__((ext_vector_type(4))) float;

__device__ __forceinline__ float bf2f(unsigned short u) {
    return __uint_as_float(((unsigned int)u) << 16);
}
__device__ __forceinline__ unsigned short f2bf(float f) {
    unsigned int u = __float_as_uint(f);
    u = (u + 0x7FFFu + ((u >> 16) & 1u)) >> 16;   // RNE
    return (unsigned short)u;
}
// pack fp32 -> (hi bf16 in low 16, lo bf16 in high 16)
__device__ __forceinline__ unsigned int packf(float v) {
    unsigned short hi = f2bf(v);
    float r = v - bf2f(hi);
    unsigned short lo = f2bf(r);
    return (unsigned int)hi | ((unsigned int)lo << 16);
}
__device__ __forceinline__ float unpackf(unsigned int u) {
    return __uint_as_float(u << 16) + __uint_as_float(u & 0xFFFF0000u);
}

__device__ __forceinline__ float ldA(const float* p, long i) { return p[i]; }
__device__ __forceinline__ float ldA(const unsigned int* p, long i) { return unpackf(p[i]); }

// ---------------- generic batched tiled fp32 GEMM (A may be packed bf16x2) ----------------
// C[m,n] = alpha * sum_k A[m,k] * (TB ? B[n,k] : B[k,n]) (+ bias[n]) (+ addp[m,n])
template<bool TB, typename AT>
__global__ __launch_bounds__(256) void gemm_k(
    const AT* __restrict__ A, long a_sb, long a_sh, int lda,
    const float* __restrict__ Bp, long b_sb, long b_sh, int ldb,
    const float* __restrict__ bias, long bias_sb, long bias_sh,
    const float* __restrict__ addp,
    float* __restrict__ C, long c_sb, long c_sh, int ldc,
    int M, int N, int K, float alpha, int nh)
{
    int z = blockIdx.z;
    int bb = z / nh, hh = z % nh;
    A  += (long)bb * a_sb + (long)hh * a_sh;
    Bp += (long)bb * b_sb + (long)hh * b_sh;
    C  += (long)bb * c_sb + (long)hh * c_sh;
    if (bias) bias += (long)bb * bias_sb + (long)hh * bias_sh;
    if (addp) addp += (long)bb * c_sb + (long)hh * c_sh;

    __shared__ float As[16][68];
    __shared__ float Bs[16][68];

    int tid = threadIdx.x;
    int tx = tid & 15, ty = tid >> 4;
    int row0 = blockIdx.y * 64, col0 = blockIdx.x * 64;

    float acc[4][4] = {};

    for (int k0 = 0; k0 < K; k0 += 16) {
#pragma unroll
        for (int r = 0; r < 4; ++r) {
            int idx = r * 256 + tid;
            int m = idx >> 4, kk = idx & 15;
            As[kk][m] = ldA(A, (long)(row0 + m) * lda + (k0 + kk));
        }
#pragma unroll
        for (int r = 0; r < 4; ++r) {
            int idx = r * 256 + tid;
            if (TB) {
                int n = idx >> 4, kk = idx & 15;
                Bs[kk][n] = Bp[(long)(col0 + n) * ldb + (k0 + kk)];
            } else {
                int kk = idx >> 6, n = idx & 63;
                Bs[kk][n] = Bp[(long)(k0 + kk) * ldb + (col0 + n)];
            }
        }
        __syncthreads();
#pragma unroll
        for (int kk = 0; kk < 16; ++kk) {
            float4 av = *(const float4*)&As[kk][ty * 4];
            float4 bv = *(const float4*)&Bs[kk][tx * 4];
            float a[4] = {av.x, av.y, av.z, av.w};
            float b[4] = {bv.x, bv.y, bv.z, bv.w};
#pragma unroll
            for (int i = 0; i < 4; ++i)
#pragma unroll
                for (int j = 0; j < 4; ++j)
                    acc[i][j] += a[i] * b[j];
        }
        __syncthreads();
    }

#pragma unroll
    for (int i = 0; i < 4; ++i) {
        int m = row0 + ty * 4 + i;
#pragma unroll
        for (int j = 0; j < 4; ++j) {
            int n = col0 + tx * 4 + j;
            float v = alpha * acc[i][j];
            if (bias) v += bias[n];
            if (addp) v += addp[(long)m * ldc + n];
            C[(long)m * ldc + n] = v;
        }
    }
}

// ---------------- Wt[z][j][i] = exp(-L1(q_i,k_j)/4) * (j<=i) ----------------
__global__ __launch_bounds__(256) void wt_kernel(const float* __restrict__ qkv,
                                                 float* __restrict__ Wt)
{
    const int tIs[10] = {0,1,1,2,2,2,3,3,3,3};
    const int tJs[10] = {0,0,1,0,1,2,0,1,2,3};
    int z = blockIdx.y;
    int b = z >> 3, h = z & 7;
    int i0 = tIs[blockIdx.x] * 128, j0 = tJs[blockIdx.x] * 128;
    int t = threadIdx.x;
    int ia = (t & 15) * 4;
    int ja = (t >> 4) * 4;

    __shared__ float qs[32][128];
    __shared__ float ks[32][128];

    const float* qb = qkv + (long)b * Ss * (3 * DIM) + h * HD;
    const float* kb = qb + DIM;

    float acc[8][8] = {};

    for (int d0 = 0; d0 < 64; d0 += 32) {
        __syncthreads();
        int col = t & 127, dg = t >> 7;
#pragma unroll
        for (int e = 0; e < 4; ++e) {
            int d = dg * 16 + e * 4;
            float4 qv = *(const float4*)&qb[(long)(i0 + col) * (3 * DIM) + d0 + d];
            float4 kv = *(const float4*)&kb[(long)(j0 + col) * (3 * DIM) + d0 + d];
            qs[d+0][col] = qv.x; qs[d+1][col] = qv.y; qs[d+2][col] = qv.z; qs[d+3][col] = qv.w;
            ks[d+0][col] = kv.x; ks[d+1][col] = kv.y; ks[d+2][col] = kv.z; ks[d+3][col] = kv.w;
        }
        __syncthreads();
#pragma unroll
        for (int d = 0; d < 32; ++d) {
            float4 q0 = *(const float4*)&qs[d][ia];
            float4 q1 = *(const float4*)&qs[d][ia + 64];
            float4 k0 = *(const float4*)&ks[d][ja];
            float4 k1 = *(const float4*)&ks[d][ja + 64];
            float qv[8] = {q0.x,q0.y,q0.z,q0.w, q1.x,q1.y,q1.z,q1.w};
            float kv[8] = {k0.x,k0.y,k0.z,k0.w, k1.x,k1.y,k1.z,k1.w};
#pragma unroll
            for (int a = 0; a < 8; ++a)
#pragma unroll
                for (int c = 0; c < 8; ++c)
                    acc[a][c] += fabsf(qv[a] - kv[c]);
        }
    }

    long zo = (long)z * Ss * Ss;
#pragma unroll
    for (int c = 0; c < 8; ++c) {
        int j = j0 + ja + (c & 3) + ((c >> 2) * 64);
        float o[8];
#pragma unroll
        for (int a = 0; a < 8; ++a) {
            int i = i0 + ia + (a & 3) + ((a >> 2) * 64);
            float e = expf(-acc[a][c] * 0.25f);
            o[a] = (j <= i) ? e : 0.0f;
        }
        *(float4*)&Wt[zo + (long)j * Ss + i0 + ia]      = make_float4(o[0],o[1],o[2],o[3]);
        *(float4*)&Wt[zo + (long)j * Ss + i0 + 64 + ia] = make_float4(o[4],o[5],o[6],o[7]);
    }
}

// ---------------- scale = 1/(n1*ninf) from Wt ----------------
// n1 = max colsum(W) = max rowsum(Wt); ninf = max rowsum(W) = max colsum(Wt)
__global__ __launch_bounds__(512) void norms_k(const float* __restrict__ Wt,
                                               float* __restrict__ scale)
{
    int z = blockIdx.x;
    int t = threadIdx.x;
    const float* M = Wt + (long)z * Ss * Ss;
    __shared__ float sA[512], sB[512];
    // col sums of Wt (coalesced)
    float cs = 0.f;
    for (int i = 0; i < Ss; ++i) cs += M[(long)i * Ss + t];
    sB[t] = cs;
    // row sums of Wt, one row per wave-iteration (coalesced within wave)
    int wave = t >> 6, lane = t & 63;
    for (int rr = 0; rr < 64; ++rr) {
        int j = rr * 8 + wave;
        const float* row = M + (long)j * Ss;
        float s = 0.f;
#pragma unroll
        for (int c = 0; c < 8; ++c) s += row[c * 64 + lane];
        for (int off = 32; off > 0; off >>= 1) s += __shfl_down(s, off);
        if (lane == 0) sA[j] = s;
    }
    __syncthreads();
    for (int off = 256; off > 0; off >>= 1) {
        if (t < off) {
            sA[t] = fmaxf(sA[t], sA[t + off]);
            sB[t] = fmaxf(sB[t], sB[t + off]);
        }
        __syncthreads();
    }
    if (t == 0) scale[z] = 1.0f / (sA[0] * sB[0]);
}

// ---------------- prep: E_A = W-I, F_A = Wt*s-I, F_B = F^T (all packed bf16x2) ----------------
__global__ __launch_bounds__(256) void prep_k(const float* __restrict__ Wt,
                                              const float* __restrict__ scale,
                                              unsigned int* __restrict__ E_A,
                                              unsigned int* __restrict__ F_A,
                                              unsigned int* __restrict__ F_B)
{
    int z = blockIdx.z;
    long zo = (long)z * Ss * Ss;
    int ti = blockIdx.y * 32, tj = blockIdx.x * 32;
    int t = threadIdx.x;
    int c = t & 31, r0 = t >> 5;
    float s = scale[z];
    __shared__ float tb[32][33];
#pragma unroll
    for (int p = 0; p < 4; ++p) {
        int r = r0 + p * 8;
        long ia = zo + (long)(ti + r) * Ss + tj + c;
        float va = Wt[ia];
        float da = ((ti + r) == (tj + c)) ? 1.f : 0.f;
        F_A[ia] = packf(va * s - da);            // F[i][j] = Wt[i][j]*s - δ
        tb[r][c] = Wt[zo + (long)(tj + r) * Ss + ti + c];
    }
    __syncthreads();
#pragma unroll
    for (int p = 0; p < 4; ++p) {
        int r = r0 + p * 8;
        int gi = ti + r, gj = tj + c;
        float vb = tb[c][r];                     // = Wt[gj][gi]
        float dd = (gi == gj) ? 1.f : 0.f;
        long oa = zo + (long)gi * Ss + gj;
        E_A[oa] = packf(vb - dd);                // E[i][j]   = W[i][j] - δ
        F_B[oa] = packf(vb * s - dd);            // F_B[n][k] = F[k][n]
    }
}

// ---------------- NS GEMM, split bf16x2: P = A@B (hi*hi + hi*lo + lo*hi), ----------------
// R = sign*(A_c + V_c + P). A row-major packed; Bmat = B^T row-major packed;
// V row-major packed read at output coords (RA may alias Vmat: same-thread
// read-before-write per element). Writes RA (row-major) and RB (transposed).
__global__ __launch_bounds__(256) void ns_gemm_k(
    const unsigned int* __restrict__ Amat,
    const unsigned int* __restrict__ Bmat,
    const unsigned int* __restrict__ Vmat,
    unsigned int* __restrict__ RA,
    unsigned int* __restrict__ RB,
    float sign)
{
    const int z = blockIdx.z;
    const long zo = (long)z * Ss * Ss;
    const int row0 = blockIdx.y * 128, col0 = blockIdx.x * 128;
    __shared__ unsigned short AsH[128][40], AsL[128][40];
    __shared__ unsigned short BsH[128][40], BsL[128][40];
    const int t = threadIdx.x;
    const int wave = t >> 6, lane = t & 63;
    const int ln = lane & 15, quad = lane >> 4;
    const int wm = (wave & 1) * 64, wn = (wave >> 1) * 64;

    f32x4 acc[4][4];
#pragma unroll
    for (int i = 0; i < 4; ++i)
#pragma unroll
        for (int j = 0; j < 4; ++j)
            acc[i][j] = (f32x4){0.f, 0.f, 0.f, 0.f};

    const int sr = t >> 2, sg = (t & 3) * 8;

    for (int k0 = 0; k0 < Ss; k0 += 32) {
        __syncthreads();
#pragma unroll
        for (int half = 0; half < 4; ++half) {
            // half 0: A row sr; 1: A row sr+64; 2: B row sr; 3: B row sr+64
            const unsigned int* src = (half < 2) ? Amat : Bmat;
            int row = ((half & 1) ? sr + 64 : sr);
            const unsigned int* p = &src[zo + (long)(row0 * (half < 2) + col0 * (half >= 2) + row) * Ss + k0 + sg];
            uint4 u0 = *(const uint4*)p;
            uint4 u1 = *(const uint4*)(p + 4);
            uint4 hi, lo;
            hi.x = (u0.x & 0xFFFFu) | (u0.y << 16);  lo.x = (u0.x >> 16) | (u0.y & 0xFFFF0000u);
            hi.y = (u0.z & 0xFFFFu) | (u0.w << 16);  lo.y = (u0.z >> 16) | (u0.w & 0xFFFF0000u);
            hi.z = (u1.x & 0xFFFFu) | (u1.y << 16);  lo.z = (u1.x >> 16) | (u1.y & 0xFFFF0000u);
            hi.w = (u1.z & 0xFFFFu) | (u1.w << 16);  lo.w = (u1.z >> 16) | (u1.w & 0xFFFF0000u);
            if (half < 2) {
                *(uint4*)&AsH[row][sg] = hi;
                *(uint4*)&AsL[row][sg] = lo;
            } else {
                *(uint4*)&BsH[row][sg] = hi;
                *(uint4*)&BsL[row][sg] = lo;
            }
        }
        __syncthreads();

        bf16x8s afH[4], afL[4], bfH[4], bfL[4];
#pragma unroll
        for (int mt = 0; mt < 4; ++mt) {
            afH[mt] = *(const bf16x8s*)&AsH[wm + mt * 16 + ln][quad * 8];
            afL[mt] = *(const bf16x8s*)&AsL[wm + mt * 16 + ln][quad * 8];
        }
#pragma unroll
        for (int nt = 0; nt < 4; ++nt) {
            bfH[nt] = *(const bf16x8s*)&BsH[wn + nt * 16 + ln][quad * 8];
            bfL[nt] = *(const bf16x8s*)&BsL[wn + nt * 16 + ln][quad * 8];
        }
#pragma unroll
        for (int mt = 0; mt < 4; ++mt)
#pragma unroll
            for (int nt = 0; nt < 4; ++nt) {
                acc[mt][nt] = __builtin_amdgcn_mfma_f32_16x16x32_bf16(afH[mt], bfH[nt], acc[mt][nt], 0, 0, 0);
                acc[mt][nt] = __builtin_amdgcn_mfma_f32_16x16x32_bf16(afH[mt], bfL[nt], acc[mt][nt], 0, 0, 0);
                acc[mt][nt] = __builtin_amdgcn_mfma_f32_16x16x32_bf16(afL[mt], bfH[nt], acc[mt][nt], 0, 0, 0);
            }
    }

#pragma unroll
    for (int mt = 0; mt < 4; ++mt) {
        const int gr0 = row0 + wm + mt * 16 + quad * 4;
#pragma unroll
        for (int nt = 0; nt < 4; ++nt) {
            const int gc = col0 + wn + nt * 16 + ln;
            unsigned int rb[4];
#pragma unroll
            for (int r = 0; r < 4; ++r) {
                const long gi = zo + (long)(gr0 + r) * Ss + gc;
                float a = unpackf(Amat[gi]);
                float v = unpackf(Vmat[gi]);
                float p = acc[mt][nt][r];
                unsigned int o = packf(sign * (a + v + p));
                RA[gi] = o;
                rb[r] = o;
            }
            *(uint4*)&RB[zo + (long)gc * Ss + gr0] = make_uint4(rb[0], rb[1], rb[2], rb[3]);
        }
    }
}

// ---------------- whitening stats: per (h,j) over (b,i) of W[b,h,i,j] = Wt[b,h,j,i] ----------------
__global__ __launch_bounds__(256) void stats2_k(const float* __restrict__ Wt,
                                                float* __restrict__ mu_is,
                                                float* __restrict__ inv_sig)
{
    int h = blockIdx.x;
    int wave = threadIdx.x >> 6, lane = threadIdx.x & 63;
    int j = blockIdx.y * 4 + wave;
    float s = 0.f, q = 0.f;
#pragma unroll
    for (int b = 0; b < 2; ++b) {
        const float* row = Wt + (((long)b * Hh + h) * Ss + j) * Ss;
#pragma unroll
        for (int c = 0; c < 2; ++c) {
            float4 v = *(const float4*)&row[lane * 4 + c * 256];
            s += v.x + v.y + v.z + v.w;
            q += v.x * v.x + v.y * v.y + v.z * v.z + v.w * v.w;
        }
    }
    for (int off = 32; off > 0; off >>= 1) {
        s += __shfl_down(s, off);
        q += __shfl_down(q, off);
    }
    if (lane == 0) {
        const float N = (float)(Bq * Ss);
        float mu = s / N;
        float var = (q - s * s / N) / (N - 1.0f);
        float is = 1.0f / sqrtf(var + 1e-5f);
        inv_sig[h * Ss + j] = is;
        mu_is[h * Ss + j] = mu * is;
    }
}

// ---------------- fold whitening ----------------
__global__ __launch_bounds__(64) void scalec_k(const float* __restrict__ mu_is,
                                               const float* __restrict__ inv_sig,
                                               float* __restrict__ ctx2,
                                               float* __restrict__ negoffs)
{
    int z = blockIdx.x;
    int h = z % Hh;
    int d = threadIdx.x;
    float* c = ctx2 + (long)z * Ss * HD;
    float off = 0.0f;
    for (int j = 0; j < Ss; ++j) {
        float v = c[(long)j * HD + d];
        off += mu_is[h * Ss + j] * v;
        c[(long)j * HD + d] = inv_sig[h * Ss + j] * v;
    }
    negoffs[z * HD + d] = -off;
}

// ---------------- ga [B,H,S,HD] -> gat [B,S,H*HD] ----------------
__global__ __launch_bounds__(256) void permute_k(const float* __restrict__ ga,
                                                 float* __restrict__ gat)
{
    long idx = (long)blockIdx.x * 256 + threadIdx.x;
    int d = idx & 63;
    long tt = idx >> 6;
    int h = tt & 7; tt >>= 3;
    int s = tt & 511;
    int b = (int)(tt >> 9);
    gat[idx] = ga[(((long)b * Hh + h) * Ss + s) * (long)HD + d];
}

extern "C" void kernel_launch(void* const* d_in, const int* in_sizes, int n_in,
                              void* d_out, int out_size, void* d_ws, size_t ws_size,
                              hipStream_t stream)
{
    const float* x      = (const float*)d_in[0];
    const float* qkv_w  = (const float*)d_in[1];
    const float* qkv_b  = (const float*)d_in[2];
    const float* proj_w = (const float*)d_in[3];
    const float* proj_b = (const float*)d_in[4];
    float* out = (float*)d_out;
    float* ws  = (float*)d_ws;

    const long SS = (long)Ss * Ss;
    const long BH = (long)Bq * Hh;

    float* qkv   = ws;
    float* Wt    = qkv + (long)Bq * Ss * 3 * DIM;
    float* ctx   = Wt + BH * SS;
    float* ctx2  = ctx + BH * Ss * HD;
    float* gat   = ctx2 + BH * Ss * HD;
    float* scale = gat + BH * Ss * HD;
    float* mu_is   = scale + 16;
    float* inv_sig = mu_is + Hh * Ss;
    float* negoffs = inv_sig + Hh * Ss;
    unsigned int* E_A = (unsigned int*)(negoffs + BH * HD);
    unsigned int* F_A = E_A + BH * SS;
    unsigned int* F_B = F_A + BH * SS;
    unsigned int* G_B = F_B + BH * SS;
    unsigned int* G_A = (unsigned int*)Wt;   // Wt dead before NS loop
    float* gaO = ctx;                        // ctx dead after step 8

    dim3 blk(256);
    const long sW = Hh * SS;
    const long sCt = (long)Hh * Ss * HD;

    // 1. qkv = x @ qkv_w^T + qkv_b
    gemm_k<true, float><<<dim3(1536 / 64, 1024 / 64, 1), blk, 0, stream>>>(
        x, 0, 0, DIM, qkv_w, 0, 0, DIM, qkv_b, 0, 0, nullptr,
        qkv, 0, 0, 3 * DIM, Bq * Ss, 3 * DIM, DIM, 1.0f, 1);

    // 2. Wt (upper tiles zeroed by memset)
    hipMemsetAsync(Wt, 0, BH * SS * sizeof(float), stream);
    wt_kernel<<<dim3(10, 16), blk, 0, stream>>>(qkv, Wt);

    // 3. scale
    norms_k<<<dim3(16), dim3(512), 0, stream>>>(Wt, scale);

    // 4. whitening stats (hoisted before NS so Wt can be reused)
    stats2_k<<<dim3(Hh, 128), blk, 0, stream>>>(Wt, mu_is, inv_sig);

    // 5. ctx = W^T @ v (hoisted)
    gemm_k<false, float><<<dim3(1, 8, 16), blk, 0, stream>>>(
        Wt, sW, SS, Ss,
        qkv + 2 * DIM, (long)Ss * 3 * DIM, (long)HD, 3 * DIM,
        nullptr, 0, 0, nullptr,
        ctx, sCt, (long)Ss * HD, HD, Ss, HD, Ss, 1.0f, Hh);

    // 6. E, F0 (packed bf16x2, dual layout for F)
    prep_k<<<dim3(16, 16, 16), blk, 0, stream>>>(Wt, scale, E_A, F_A, F_B);

    // 7. Newton-Schulz, delta form, split precision:
    //    G = -(E + F + E@F);  F' = F + G + F@G
    {
        unsigned int *fA = F_A, *fB = F_B, *gA = G_A, *gB = G_B;
        for (int it = 0; it < 5; ++it) {
            ns_gemm_k<<<dim3(4, 4, 16), blk, 0, stream>>>(E_A, fB, fA, gA, gB, -1.0f);
            ns_gemm_k<<<dim3(4, 4, 16), blk, 0, stream>>>(fA, gB, gA, gA, fB, 1.0f);
            unsigned int* tmp = fA; fA = gA; gA = tmp;   // F' now in (fA, fB)
        }
        // 8. ctx2 = ctx + F @ ctx   (== W_inv @ ctx)
        gemm_k<false, unsigned int><<<dim3(1, 8, 16), blk, 0, stream>>>(
            fA, sW, SS, Ss, ctx, sCt, (long)Ss * HD, HD,
            nullptr, 0, 0, ctx,
            ctx2, sCt, (long)Ss * HD, HD, Ss, HD, Ss, 1.0f, Hh);
    }

    // 9. fold whitening into ctx2 + column offsets
    scalec_k<<<dim3(16), dim3(64), 0, stream>>>(mu_is, inv_sig, ctx2, negoffs);

    // 10. ga = c2s + E @ c2s + negoffs   (== W_norm @ ctx2)
    gemm_k<false, unsigned int><<<dim3(1, 8, 16), blk, 0, stream>>>(
        E_A, sW, SS, Ss, ctx2, sCt, (long)Ss * HD, HD,
        negoffs, (long)Hh * HD, (long)HD, ctx2,
        gaO, sCt, (long)Ss * HD, HD, Ss, HD, Ss, 1.0f, Hh);

    // 11. permute + proj
    permute_k<<<dim3((Bq * Ss * DIM) / 256), blk, 0, stream>>>(gaO, gat);
    gemm_k<true, float><<<dim3(512 / 64, 1024 / 64, 1), blk, 0, stream>>>(
        gat, 0, 0, DIM, proj_w, 0, 0, DIM, proj_b, 0, 0, nullptr,
        out, 0, 0, DIM, Bq * Ss, DIM, DIM, 1.0f, 1);
}

// Round 4
// 609.889 us; speedup vs baseline: 1.8155x; 1.2899x over previous
//
#include <hip/hip_runtime.h>

#define Bq 2
#define Hh 8
#define Ss 512
#define HD 64
#define DIM 512

using bf16x8s = __attribute__((ext_vector_type(8))) short;
using f32x4   = __attribute__((ext_vector_type(4))) float;

__device__ __forceinline__ float bf2f(unsigned short u) {
    return __uint_as_float(((unsigned int)u) << 16);
}
__device__ __forceinline__ unsigned short f2bf(float f) {
    unsigned int u = __float_as_uint(f);
    u = (u + 0x7FFFu + ((u >> 16) & 1u)) >> 16;   // RNE
    return (unsigned short)u;
}
__device__ __forceinline__ unsigned int packf(float v) {
    unsigned short hi = f2bf(v);
    float r = v - bf2f(hi);
    unsigned short lo = f2bf(r);
    return (unsigned int)hi | ((unsigned int)lo << 16);
}
__device__ __forceinline__ float unpackf(unsigned int u) {
    return __uint_as_float(u << 16) + __uint_as_float(u & 0xFFFF0000u);
}

// ============ mm_k: C[M,N] = A @ B^T + bias, fp32 in/out, split-bf16x2 MFMA ============
// A [M][K] row-major fp32; B [N][K] row-major fp32 (i.e. B-layout); K = 512 assumed mult of 32.
__global__ __launch_bounds__(256) void mm_k(
    const float* __restrict__ A, const float* __restrict__ B,
    const float* __restrict__ bias, float* __restrict__ C,
    int K, int ldc)
{
    const int row0 = blockIdx.y * 128, col0 = blockIdx.x * 128;
    __shared__ unsigned short AsH[128][40], AsL[128][40];
    __shared__ unsigned short BsH[128][40], BsL[128][40];
    const int t = threadIdx.x;
    const int wave = t >> 6, lane = t & 63;
    const int ln = lane & 15, quad = lane >> 4;
    const int wm = (wave & 1) * 64, wn = (wave >> 1) * 64;

    f32x4 acc[4][4];
#pragma unroll
    for (int i = 0; i < 4; ++i)
#pragma unroll
        for (int j = 0; j < 4; ++j)
            acc[i][j] = (f32x4){0.f, 0.f, 0.f, 0.f};

    const int sr = t >> 2, sg = (t & 3) * 8;

    for (int k0 = 0; k0 < K; k0 += 32) {
        __syncthreads();
#pragma unroll
        for (int half = 0; half < 4; ++half) {
            const float* src = (half < 2) ? A : B;
            int base = (half < 2) ? row0 : col0;
            int row = sr + ((half & 1) ? 64 : 0);
            const float* p = &src[(long)(base + row) * K + k0 + sg];
            float4 f0 = *(const float4*)p;
            float4 f1 = *(const float4*)(p + 4);
            float fv[8] = {f0.x, f0.y, f0.z, f0.w, f1.x, f1.y, f1.z, f1.w};
            unsigned short hv[8], lv[8];
#pragma unroll
            for (int e = 0; e < 8; ++e) {
                hv[e] = f2bf(fv[e]);
                lv[e] = f2bf(fv[e] - bf2f(hv[e]));
            }
            uint4 H, L;
            H.x = hv[0] | (hv[1] << 16); H.y = hv[2] | (hv[3] << 16);
            H.z = hv[4] | (hv[5] << 16); H.w = hv[6] | (hv[7] << 16);
            L.x = lv[0] | (lv[1] << 16); L.y = lv[2] | (lv[3] << 16);
            L.z = lv[4] | (lv[5] << 16); L.w = lv[6] | (lv[7] << 16);
            if (half < 2) { *(uint4*)&AsH[row][sg] = H; *(uint4*)&AsL[row][sg] = L; }
            else          { *(uint4*)&BsH[row][sg] = H; *(uint4*)&BsL[row][sg] = L; }
        }
        __syncthreads();

        bf16x8s afH[4], afL[4], bfH[4], bfL[4];
#pragma unroll
        for (int mt = 0; mt < 4; ++mt) {
            afH[mt] = *(const bf16x8s*)&AsH[wm + mt * 16 + ln][quad * 8];
            afL[mt] = *(const bf16x8s*)&AsL[wm + mt * 16 + ln][quad * 8];
        }
#pragma unroll
        for (int nt = 0; nt < 4; ++nt) {
            bfH[nt] = *(const bf16x8s*)&BsH[wn + nt * 16 + ln][quad * 8];
            bfL[nt] = *(const bf16x8s*)&BsL[wn + nt * 16 + ln][quad * 8];
        }
#pragma unroll
        for (int mt = 0; mt < 4; ++mt)
#pragma unroll
            for (int nt = 0; nt < 4; ++nt) {
                acc[mt][nt] = __builtin_amdgcn_mfma_f32_16x16x32_bf16(afH[mt], bfH[nt], acc[mt][nt], 0, 0, 0);
                acc[mt][nt] = __builtin_amdgcn_mfma_f32_16x16x32_bf16(afH[mt], bfL[nt], acc[mt][nt], 0, 0, 0);
                acc[mt][nt] = __builtin_amdgcn_mfma_f32_16x16x32_bf16(afL[mt], bfH[nt], acc[mt][nt], 0, 0, 0);
            }
    }

#pragma unroll
    for (int mt = 0; mt < 4; ++mt) {
        const int gr0 = row0 + wm + mt * 16 + quad * 4;
#pragma unroll
        for (int nt = 0; nt < 4; ++nt) {
            const int gc = col0 + wn + nt * 16 + ln;
            float bb = bias ? bias[gc] : 0.f;
#pragma unroll
            for (int r = 0; r < 4; ++r)
                C[(long)(gr0 + r) * ldc + gc] = acc[mt][nt][r] + bb;
        }
    }
}

// ============ wt_kernel: Wt[z][j][i] = exp(-L1(q_i,k_j)/4)*(j<=i), 128x128 tiles ============
__global__ __launch_bounds__(256) void wt_kernel(const float* __restrict__ qkv,
                                                 float* __restrict__ Wt)
{
    int z = blockIdx.y;
    int b = z >> 3, h = z & 7;
    int ti = blockIdx.x >> 2, tj = blockIdx.x & 3;
    int i0 = ti * 128, j0 = tj * 128;
    int t = threadIdx.x;
    long zo = (long)z * Ss * Ss;

    if (tj > ti) {   // fully masked: zero-fill
        float4 zz = make_float4(0.f, 0.f, 0.f, 0.f);
#pragma unroll
        for (int r = 0; r < 16; ++r) {
            int idx = r * 256 + t;          // 4096 float4 slots in 128x128
            int row = idx >> 5, col4 = idx & 31;
            *(float4*)&Wt[zo + (long)(j0 + row) * Ss + i0 + col4 * 4] = zz;
        }
        return;
    }

    int ia = (t & 15) * 4;
    int ja = (t >> 4) * 4;
    __shared__ float qs[32][128];
    __shared__ float ks[32][128];
    const float* qb = qkv + (long)b * Ss * (3 * DIM) + h * HD;
    const float* kb = qb + DIM;

    float acc[8][8] = {};

    for (int d0 = 0; d0 < 64; d0 += 32) {
        __syncthreads();
        int col = t & 127, dg = t >> 7;
#pragma unroll
        for (int e = 0; e < 4; ++e) {
            int d = dg * 16 + e * 4;
            float4 qv = *(const float4*)&qb[(long)(i0 + col) * (3 * DIM) + d0 + d];
            float4 kv = *(const float4*)&kb[(long)(j0 + col) * (3 * DIM) + d0 + d];
            qs[d+0][col] = qv.x; qs[d+1][col] = qv.y; qs[d+2][col] = qv.z; qs[d+3][col] = qv.w;
            ks[d+0][col] = kv.x; ks[d+1][col] = kv.y; ks[d+2][col] = kv.z; ks[d+3][col] = kv.w;
        }
        __syncthreads();
#pragma unroll
        for (int d = 0; d < 32; ++d) {
            float4 q0 = *(const float4*)&qs[d][ia];
            float4 q1 = *(const float4*)&qs[d][ia + 64];
            float4 k0 = *(const float4*)&ks[d][ja];
            float4 k1 = *(const float4*)&ks[d][ja + 64];
            float qv[8] = {q0.x,q0.y,q0.z,q0.w, q1.x,q1.y,q1.z,q1.w};
            float kv[8] = {k0.x,k0.y,k0.z,k0.w, k1.x,k1.y,k1.z,k1.w};
#pragma unroll
            for (int a = 0; a < 8; ++a)
#pragma unroll
                for (int c = 0; c < 8; ++c)
                    acc[a][c] += fabsf(qv[a] - kv[c]);
        }
    }

#pragma unroll
    for (int c = 0; c < 8; ++c) {
        int j = j0 + ja + (c & 3) + ((c >> 2) * 64);
        float o[8];
#pragma unroll
        for (int a = 0; a < 8; ++a) {
            int i = i0 + ia + (a & 3) + ((a >> 2) * 64);
            float e = expf(-acc[a][c] * 0.25f);
            o[a] = (j <= i) ? e : 0.0f;
        }
        *(float4*)&Wt[zo + (long)j * Ss + i0 + ia]      = make_float4(o[0],o[1],o[2],o[3]);
        *(float4*)&Wt[zo + (long)j * Ss + i0 + 64 + ia] = make_float4(o[4],o[5],o[6],o[7]);
    }
}

// ============ vt_pack: vT[z][d][k] = packf(v[z][k][d]) ============
__global__ __launch_bounds__(256) void vt_pack(const float* __restrict__ qkv,
                                               unsigned int* __restrict__ vT)
{
    int z = blockIdx.z;
    int b = z >> 3, h = z & 7;
    int kt = blockIdx.x * 32, dt = blockIdx.y * 32;
    int t = threadIdx.x;
    int d = t & 31, kr = t >> 5;
    __shared__ float sT[32][33];
#pragma unroll
    for (int p = 0; p < 4; ++p) {
        int kk = kr + p * 8;
        sT[kk][d] = qkv[(long)b * (Ss * 3 * DIM) + (long)(kt + kk) * (3 * DIM) + 2 * DIM + h * HD + dt + d];
    }
    __syncthreads();
#pragma unroll
    for (int p = 0; p < 4; ++p) {
        int dd = kr + p * 8;
        vT[(long)z * (HD * Ss) + (long)(dt + dd) * Ss + kt + d] = packf(sT[d][dd]);
    }
}

// ============ norms: n1 = max rowsum(Wt), ninf = max colsum(Wt) ============
__global__ __launch_bounds__(256) void normsA_k(const float* __restrict__ Wt,
                                                float* __restrict__ colsum,
                                                unsigned int* __restrict__ rowmaxb)
{
    int z = blockIdx.y;
    int r0 = blockIdx.x * 64;
    int t = threadIdx.x;
    const float* M = Wt + (long)z * Ss * Ss;
    // partial column sums over rows r0..r0+63
    float c0 = 0.f, c1 = 0.f;
    for (int r = 0; r < 64; ++r) {
        const float* row = M + (long)(r0 + r) * Ss;
        c0 += row[t];
        c1 += row[t + 256];
    }
    atomicAdd(&colsum[z * Ss + t], c0);
    atomicAdd(&colsum[z * Ss + t + 256], c1);
    // complete row sums for rows r0..r0+63
    int wave = t >> 6, lane = t & 63;
    float lmax = 0.f;
    for (int rr = 0; rr < 16; ++rr) {
        int row = r0 + wave * 16 + rr;
        const float* rp = M + (long)row * Ss;
        float s = 0.f;
#pragma unroll
        for (int c = 0; c < 8; ++c) s += rp[c * 64 + lane];
        for (int off = 32; off > 0; off >>= 1) s += __shfl_down(s, off);
        if (lane == 0) lmax = fmaxf(lmax, s);
    }
    if (lane == 0) atomicMax(&rowmaxb[z], __float_as_uint(lmax));
}

__global__ __launch_bounds__(512) void normsB_k(const float* __restrict__ colsum,
                                                const unsigned int* __restrict__ rowmaxb,
                                                float* __restrict__ nn,
                                                float* __restrict__ scale)
{
    int z = blockIdx.x;
    int t = threadIdx.x;
    __shared__ float sm[512];
    sm[t] = colsum[z * Ss + t];
    __syncthreads();
    for (int off = 256; off > 0; off >>= 1) {
        if (t < off) sm[t] = fmaxf(sm[t], sm[t + off]);
        __syncthreads();
    }
    if (t == 0) {
        float n1 = __uint_as_float(rowmaxb[z]);
        float v = n1 * sm[0];
        nn[z] = v;
        scale[z] = 1.0f / v;
    }
}

// ============ stats: per (h,j) over (b,i): mu, inv_sig of W[b,h,i,j] = Wt[b,h,j,i] ============
__global__ __launch_bounds__(256) void stats2_k(const float* __restrict__ Wt,
                                                float* __restrict__ mu_out,
                                                float* __restrict__ inv_sig)
{
    int h = blockIdx.x;
    int wave = threadIdx.x >> 6, lane = threadIdx.x & 63;
    int j = blockIdx.y * 4 + wave;
    float s = 0.f, q = 0.f;
#pragma unroll
    for (int b = 0; b < 2; ++b) {
        const float* row = Wt + (((long)b * Hh + h) * Ss + j) * Ss;
#pragma unroll
        for (int c = 0; c < 2; ++c) {
            float4 v = *(const float4*)&row[lane * 4 + c * 256];
            s += v.x + v.y + v.z + v.w;
            q += v.x * v.x + v.y * v.y + v.z * v.z + v.w * v.w;
        }
    }
    for (int off = 32; off > 0; off >>= 1) {
        s += __shfl_down(s, off);
        q += __shfl_down(q, off);
    }
    if (lane == 0) {
        const float N = (float)(Bq * Ss);
        float mu = s / N;
        float var = (q - s * s / N) / (N - 1.0f);
        inv_sig[h * Ss + j] = 1.0f / sqrtf(var + 1e-5f);
        mu_out[h * Ss + j] = mu;
    }
}

// ============ prep: E_A = W-I, F_A = Wt*s-I, F_B = F^T (packed bf16x2) ============
__global__ __launch_bounds__(256) void prep_k(const float* __restrict__ Wt,
                                              const float* __restrict__ scale,
                                              unsigned int* __restrict__ E_A,
                                              unsigned int* __restrict__ F_A,
                                              unsigned int* __restrict__ F_B)
{
    int z = blockIdx.z;
    long zo = (long)z * Ss * Ss;
    int ti = blockIdx.y * 32, tj = blockIdx.x * 32;
    int t = threadIdx.x;
    int c = t & 31, r0 = t >> 5;
    float s = scale[z];
    __shared__ float tb[32][33];
#pragma unroll
    for (int p = 0; p < 4; ++p) {
        int r = r0 + p * 8;
        long ia = zo + (long)(ti + r) * Ss + tj + c;
        float va = Wt[ia];
        float da = ((ti + r) == (tj + c)) ? 1.f : 0.f;
        F_A[ia] = packf(va * s - da);
        tb[r][c] = Wt[zo + (long)(tj + r) * Ss + ti + c];
    }
    __syncthreads();
#pragma unroll
    for (int p = 0; p < 4; ++p) {
        int r = r0 + p * 8;
        int gi = ti + r, gj = tj + c;
        float vb = tb[c][r];
        float dd = (gi == gj) ? 1.f : 0.f;
        long oa = zo + (long)gi * Ss + gj;
        E_A[oa] = packf(vb - dd);
        F_B[oa] = packf(vb * s - dd);
    }
}

// ============ NS GEMM (unchanged from round 3) ============
__global__ __launch_bounds__(256) void ns_gemm_k(
    const unsigned int* __restrict__ Amat,
    const unsigned int* __restrict__ Bmat,
    const unsigned int* __restrict__ Vmat,
    unsigned int* __restrict__ RA,
    unsigned int* __restrict__ RB,
    float sign)
{
    const int z = blockIdx.z;
    const long zo = (long)z * Ss * Ss;
    const int row0 = blockIdx.y * 128, col0 = blockIdx.x * 128;
    __shared__ unsigned short AsH[128][40], AsL[128][40];
    __shared__ unsigned short BsH[128][40], BsL[128][40];
    const int t = threadIdx.x;
    const int wave = t >> 6, lane = t & 63;
    const int ln = lane & 15, quad = lane >> 4;
    const int wm = (wave & 1) * 64, wn = (wave >> 1) * 64;

    f32x4 acc[4][4];
#pragma unroll
    for (int i = 0; i < 4; ++i)
#pragma unroll
        for (int j = 0; j < 4; ++j)
            acc[i][j] = (f32x4){0.f, 0.f, 0.f, 0.f};

    const int sr = t >> 2, sg = (t & 3) * 8;

    for (int k0 = 0; k0 < Ss; k0 += 32) {
        __syncthreads();
#pragma unroll
        for (int half = 0; half < 4; ++half) {
            const unsigned int* src = (half < 2) ? Amat : Bmat;
            int row = ((half & 1) ? sr + 64 : sr);
            const unsigned int* p = &src[zo + (long)(row0 * (half < 2) + col0 * (half >= 2) + row) * Ss + k0 + sg];
            uint4 u0 = *(const uint4*)p;
            uint4 u1 = *(const uint4*)(p + 4);
            uint4 hi, lo;
            hi.x = (u0.x & 0xFFFFu) | (u0.y << 16);  lo.x = (u0.x >> 16) | (u0.y & 0xFFFF0000u);
            hi.y = (u0.z & 0xFFFFu) | (u0.w << 16);  lo.y = (u0.z >> 16) | (u0.w & 0xFFFF0000u);
            hi.z = (u1.x & 0xFFFFu) | (u1.y << 16);  lo.z = (u1.x >> 16) | (u1.y & 0xFFFF0000u);
            hi.w = (u1.z & 0xFFFFu) | (u1.w << 16);  lo.w = (u1.z >> 16) | (u1.w & 0xFFFF0000u);
            if (half < 2) { *(uint4*)&AsH[row][sg] = hi; *(uint4*)&AsL[row][sg] = lo; }
            else          { *(uint4*)&BsH[row][sg] = hi; *(uint4*)&BsL[row][sg] = lo; }
        }
        __syncthreads();

        bf16x8s afH[4], afL[4], bfH[4], bfL[4];
#pragma unroll
        for (int mt = 0; mt < 4; ++mt) {
            afH[mt] = *(const bf16x8s*)&AsH[wm + mt * 16 + ln][quad * 8];
            afL[mt] = *(const bf16x8s*)&AsL[wm + mt * 16 + ln][quad * 8];
        }
#pragma unroll
        for (int nt = 0; nt < 4; ++nt) {
            bfH[nt] = *(const bf16x8s*)&BsH[wn + nt * 16 + ln][quad * 8];
            bfL[nt] = *(const bf16x8s*)&BsL[wn + nt * 16 + ln][quad * 8];
        }
#pragma unroll
        for (int mt = 0; mt < 4; ++mt)
#pragma unroll
            for (int nt = 0; nt < 4; ++nt) {
                acc[mt][nt] = __builtin_amdgcn_mfma_f32_16x16x32_bf16(afH[mt], bfH[nt], acc[mt][nt], 0, 0, 0);
                acc[mt][nt] = __builtin_amdgcn_mfma_f32_16x16x32_bf16(afH[mt], bfL[nt], acc[mt][nt], 0, 0, 0);
                acc[mt][nt] = __builtin_amdgcn_mfma_f32_16x16x32_bf16(afL[mt], bfH[nt], acc[mt][nt], 0, 0, 0);
            }
    }

#pragma unroll
    for (int mt = 0; mt < 4; ++mt) {
        const int gr0 = row0 + wm + mt * 16 + quad * 4;
#pragma unroll
        for (int nt = 0; nt < 4; ++nt) {
            const int gc = col0 + wn + nt * 16 + ln;
            unsigned int rb[4];
#pragma unroll
            for (int r = 0; r < 4; ++r) {
                const long gi = zo + (long)(gr0 + r) * Ss + gc;
                float a = unpackf(Amat[gi]);
                float v = unpackf(Vmat[gi]);
                float p = acc[mt][nt][r];
                unsigned int o = packf(sign * (a + v + p));
                RA[gi] = o;
                rb[r] = o;
            }
            *(uint4*)&RB[zo + (long)gc * Ss + gr0] = make_uint4(rb[0], rb[1], rb[2], rb[3]);
        }
    }
}

// ============ skinny_k<MODE>: 64x64 tile, P = A@B (packed split), fused epilogues ============
// MODE 0: ctx  = (V + P) * nn[z]          V = v (in qkv, ld 1536); out Cf=ctx + CtP=ctxT
// MODE 1: c2s  = inv_sig[h,m] * (V + P)   V = ctx (ld 64);         out Cf=c2s + CtP=c2sT
// MODE 2: gat  = V + P + negoffs[z,n]     V = c2s (ld 64);         out Cf=gat[(b*512+m)*512+h*64+n]
template<int MODE>
__global__ __launch_bounds__(256) void skinny_k(
    const unsigned int* __restrict__ Ap,
    const unsigned int* __restrict__ Bp,
    const float* __restrict__ Vf,
    float* __restrict__ Cf,
    unsigned int* __restrict__ CtP,
    const float* __restrict__ aux)
{
    const int z = blockIdx.y;
    const int b = z >> 3, h = z & 7;
    const int m0 = blockIdx.x * 64;
    const long zA = (long)z * Ss * Ss;
    const long zB = (long)z * HD * Ss;

    __shared__ unsigned short AsH[64][40], AsL[64][40];
    __shared__ unsigned short BsH[64][40], BsL[64][40];
    const int t = threadIdx.x;
    const int wave = t >> 6, lane = t & 63;
    const int ln = lane & 15, quad = lane >> 4;
    const int sr = t >> 2, sg = (t & 3) * 8;

    f32x4 acc[4];
#pragma unroll
    for (int i = 0; i < 4; ++i) acc[i] = (f32x4){0.f, 0.f, 0.f, 0.f};

    for (int k0 = 0; k0 < Ss; k0 += 32) {
        __syncthreads();
#pragma unroll
        for (int half = 0; half < 2; ++half) {
            const unsigned int* p = half ? &Bp[zB + (long)sr * Ss + k0 + sg]
                                         : &Ap[zA + (long)(m0 + sr) * Ss + k0 + sg];
            uint4 u0 = *(const uint4*)p;
            uint4 u1 = *(const uint4*)(p + 4);
            uint4 hi, lo;
            hi.x = (u0.x & 0xFFFFu) | (u0.y << 16);  lo.x = (u0.x >> 16) | (u0.y & 0xFFFF0000u);
            hi.y = (u0.z & 0xFFFFu) | (u0.w << 16);  lo.y = (u0.z >> 16) | (u0.w & 0xFFFF0000u);
            hi.z = (u1.x & 0xFFFFu) | (u1.y << 16);  lo.z = (u1.x >> 16) | (u1.y & 0xFFFF0000u);
            hi.w = (u1.z & 0xFFFFu) | (u1.w << 16);  lo.w = (u1.z >> 16) | (u1.w & 0xFFFF0000u);
            if (half) { *(uint4*)&BsH[sr][sg] = hi; *(uint4*)&BsL[sr][sg] = lo; }
            else      { *(uint4*)&AsH[sr][sg] = hi; *(uint4*)&AsL[sr][sg] = lo; }
        }
        __syncthreads();

        bf16x8s afH = *(const bf16x8s*)&AsH[wave * 16 + ln][quad * 8];
        bf16x8s afL = *(const bf16x8s*)&AsL[wave * 16 + ln][quad * 8];
#pragma unroll
        for (int nt = 0; nt < 4; ++nt) {
            bf16x8s bH = *(const bf16x8s*)&BsH[nt * 16 + ln][quad * 8];
            bf16x8s bL = *(const bf16x8s*)&BsL[nt * 16 + ln][quad * 8];
            acc[nt] = __builtin_amdgcn_mfma_f32_16x16x32_bf16(afH, bH, acc[nt], 0, 0, 0);
            acc[nt] = __builtin_amdgcn_mfma_f32_16x16x32_bf16(afH, bL, acc[nt], 0, 0, 0);
            acc[nt] = __builtin_amdgcn_mfma_f32_16x16x32_bf16(afL, bH, acc[nt], 0, 0, 0);
        }
    }

    const int gr = wave * 16 + quad * 4;
#pragma unroll
    for (int nt = 0; nt < 4; ++nt) {
        const int col = nt * 16 + ln;
        unsigned int rb[4];
#pragma unroll
        for (int r = 0; r < 4; ++r) {
            const int m = m0 + gr + r;
            float vv, val;
            if (MODE == 0) {
                vv = Vf[(long)b * (Ss * 3 * DIM) + (long)m * (3 * DIM) + h * HD + col];
                val = (vv + acc[nt][r]) * aux[z];
            } else if (MODE == 1) {
                vv = Vf[zB + (long)m * HD + col];
                val = aux[h * Ss + m] * (vv + acc[nt][r]);
            } else {
                vv = Vf[zB + (long)m * HD + col];
                val = vv + acc[nt][r] + aux[z * HD + col];
            }
            if (MODE < 2) {
                Cf[zB + (long)m * HD + col] = val;
                rb[r] = packf(val);
            } else {
                Cf[(long)b * (Ss * DIM) + (long)m * DIM + h * HD + col] = val;
            }
        }
        if (MODE < 2)
            *(uint4*)&CtP[zB + (long)col * Ss + m0 + gr] = make_uint4(rb[0], rb[1], rb[2], rb[3]);
    }
}

// ============ negoff: negoffs[z,d] = -sum_j mu[h,j] * c2s[z,j,d] ============
__global__ __launch_bounds__(256) void negoff_k(const float* __restrict__ mu,
                                                const float* __restrict__ c2s,
                                                float* __restrict__ negoffs)
{
    int z = blockIdx.x;
    int h = z & 7;
    int t = threadIdx.x;
    int part = t >> 6, d = t & 63;
    float s = 0.f;
    for (int j = part * 128; j < part * 128 + 128; ++j)
        s += mu[h * Ss + j] * c2s[(long)z * (Ss * HD) + (long)j * HD + d];
    __shared__ float red[4][64];
    red[part][d] = s;
    __syncthreads();
    if (t < 64)
        negoffs[z * HD + t] = -(red[0][t] + red[1][t] + red[2][t] + red[3][t]);
}

extern "C" void kernel_launch(void* const* d_in, const int* in_sizes, int n_in,
                              void* d_out, int out_size, void* d_ws, size_t ws_size,
                              hipStream_t stream)
{
    const float* x      = (const float*)d_in[0];
    const float* qkv_w  = (const float*)d_in[1];
    const float* qkv_b  = (const float*)d_in[2];
    const float* proj_w = (const float*)d_in[3];
    const float* proj_b = (const float*)d_in[4];
    float* out = (float*)d_out;
    float* ws  = (float*)d_ws;

    const long SS = (long)Ss * Ss;          // 262144
    const long BH = (long)Bq * Hh;          // 16
    const long CT = (long)HD * Ss;          // 32768

    float* qkv  = ws;                                    // 1,572,864 f
    float* Wt   = qkv + (long)Bq * Ss * 3 * DIM;         // 4,194,304 f
    float* ctx  = Wt + BH * SS;                          // 1,048,576 f
    unsigned int* ctxT = (unsigned int*)(ctx + BH * CT); //   524,288 u
    unsigned int* vT   = ctxT + BH * CT;                 //   524,288 u
    unsigned int* E_A  = vT + BH * CT;                   // 4,194,304 u
    unsigned int* F_A  = E_A + BH * SS;
    unsigned int* F_B  = F_A + BH * SS;
    unsigned int* G_B  = F_B + BH * SS;
    float* colsum = (float*)(G_B + BH * SS);             // 8192 f
    unsigned int* rowmaxb = (unsigned int*)(colsum + Hh * 2 * Ss);  // 16 u
    float* nn      = (float*)(rowmaxb + 16);
    float* scale   = nn + 16;
    float* mu      = scale + 16;                         // 4096
    float* inv_sig = mu + Hh * Ss;                       // 4096
    float* negoffs = inv_sig + Hh * Ss;                  // 1024
    // overlays
    unsigned int* G_A = (unsigned int*)Wt;               // Wt dead after prep
    float* c2s = qkv;                                    // qkv dead after skinny<0>
    unsigned int* c2sT = (unsigned int*)(qkv + BH * CT);
    float* gat = (float*)vT;                             // vT dead after skinny<0>

    dim3 blk(256);

    // 1. qkv = x @ qkv_w^T + qkv_b  (MFMA split)
    mm_k<<<dim3(1536 / 128, 1024 / 128), blk, 0, stream>>>(x, qkv_w, qkv_b, qkv, DIM, 3 * DIM);

    // 2. Wt (zero-fill path handles upper tiles)
    wt_kernel<<<dim3(16, 16), blk, 0, stream>>>(qkv, Wt);

    // 3. vT = packed v^T
    vt_pack<<<dim3(16, 2, 16), blk, 0, stream>>>(qkv, vT);

    // 4. norms -> nn, scale
    hipMemsetAsync(colsum, 0, (Hh * 2 * Ss + 16) * sizeof(float), stream);
    normsA_k<<<dim3(8, 16), blk, 0, stream>>>(Wt, colsum, rowmaxb);
    normsB_k<<<dim3(16), dim3(512), 0, stream>>>(colsum, rowmaxb, nn, scale);

    // 5. stats -> mu, inv_sig
    stats2_k<<<dim3(Hh, 128), blk, 0, stream>>>(Wt, mu, inv_sig);

    // 6. E, F0 packed
    prep_k<<<dim3(16, 16, 16), blk, 0, stream>>>(Wt, scale, E_A, F_A, F_B);

    // 7. ctx = Wt @ v = (F@v + v)*nn   (skinny MODE 0)
    skinny_k<0><<<dim3(8, 16), blk, 0, stream>>>(F_A, vT, qkv + 2 * DIM, ctx, ctxT, nn);

    // 8. Newton-Schulz: G = -(E+F+E@F); F' = F+G+F@G
    unsigned int *fA = F_A, *fB = F_B, *gA = G_A, *gB = G_B;
    for (int it = 0; it < 5; ++it) {
        ns_gemm_k<<<dim3(4, 4, 16), blk, 0, stream>>>(E_A, fB, fA, gA, gB, -1.0f);
        ns_gemm_k<<<dim3(4, 4, 16), blk, 0, stream>>>(fA, gB, gA, gA, fB, 1.0f);
        unsigned int* tmp = fA; fA = gA; gA = tmp;
    }

    // 9. c2s = inv_sig * (ctx + F@ctx)   (skinny MODE 1)
    skinny_k<1><<<dim3(8, 16), blk, 0, stream>>>(fA, ctxT, ctx, c2s, c2sT, inv_sig);

    // 10. negoffs
    negoff_k<<<dim3(16), blk, 0, stream>>>(mu, c2s, negoffs);

    // 11. gat = c2s + E@c2s + negoffs, written in [B,S,DIM] layout (skinny MODE 2)
    skinny_k<2><<<dim3(8, 16), blk, 0, stream>>>(E_A, c2sT, c2s, gat, nullptr, negoffs);

    // 12. out = gat @ proj_w^T + proj_b
    mm_k<<<dim3(512 / 128, 1024 / 128), blk, 0, stream>>>(gat, proj_w, proj_b, out, DIM, DIM);
}

// Round 5
// 428.788 us; speedup vs baseline: 2.5822x; 1.4224x over previous
//
#include <hip/hip_runtime.h>

#define Bq 2
#define Hh 8
#define Ss 512
#define HD 64
#define DIM 512

using bf16x8s = __attribute__((ext_vector_type(8))) short;
using f32x4   = __attribute__((ext_vector_type(4))) float;
typedef _Float16 f16x8 __attribute__((ext_vector_type(8)));

__device__ __forceinline__ float bf2f(unsigned short u) {
    return __uint_as_float(((unsigned int)u) << 16);
}
__device__ __forceinline__ unsigned short f2bf(float f) {
    unsigned int u = __float_as_uint(f);
    u = (u + 0x7FFFu + ((u >> 16) & 1u)) >> 16;   // RNE
    return (unsigned short)u;
}

// ============ mm_k: C[M,N] = A @ B^T + bias, fp32 in/out, split-bf16x2 MFMA ============
__global__ __launch_bounds__(256) void mm_k(
    const float* __restrict__ A, const float* __restrict__ B,
    const float* __restrict__ bias, float* __restrict__ C,
    int K, int ldc)
{
    const int row0 = blockIdx.y * 128, col0 = blockIdx.x * 128;
    __shared__ unsigned short AsH[128][40], AsL[128][40];
    __shared__ unsigned short BsH[128][40], BsL[128][40];
    const int t = threadIdx.x;
    const int wave = t >> 6, lane = t & 63;
    const int ln = lane & 15, quad = lane >> 4;
    const int wm = (wave & 1) * 64, wn = (wave >> 1) * 64;

    f32x4 acc[4][4];
#pragma unroll
    for (int i = 0; i < 4; ++i)
#pragma unroll
        for (int j = 0; j < 4; ++j)
            acc[i][j] = (f32x4){0.f, 0.f, 0.f, 0.f};

    const int sr = t >> 2, sg = (t & 3) * 8;

    for (int k0 = 0; k0 < K; k0 += 32) {
        __syncthreads();
#pragma unroll
        for (int half = 0; half < 4; ++half) {
            const float* src = (half < 2) ? A : B;
            int base = (half < 2) ? row0 : col0;
            int row = sr + ((half & 1) ? 64 : 0);
            const float* p = &src[(long)(base + row) * K + k0 + sg];
            float4 f0 = *(const float4*)p;
            float4 f1 = *(const float4*)(p + 4);
            float fv[8] = {f0.x, f0.y, f0.z, f0.w, f1.x, f1.y, f1.z, f1.w};
            unsigned short hv[8], lv[8];
#pragma unroll
            for (int e = 0; e < 8; ++e) {
                hv[e] = f2bf(fv[e]);
                lv[e] = f2bf(fv[e] - bf2f(hv[e]));
            }
            uint4 H, L;
            H.x = hv[0] | (hv[1] << 16); H.y = hv[2] | (hv[3] << 16);
            H.z = hv[4] | (hv[5] << 16); H.w = hv[6] | (hv[7] << 16);
            L.x = lv[0] | (lv[1] << 16); L.y = lv[2] | (lv[3] << 16);
            L.z = lv[4] | (lv[5] << 16); L.w = lv[6] | (lv[7] << 16);
            if (half < 2) { *(uint4*)&AsH[row][sg] = H; *(uint4*)&AsL[row][sg] = L; }
            else          { *(uint4*)&BsH[row][sg] = H; *(uint4*)&BsL[row][sg] = L; }
        }
        __syncthreads();

        bf16x8s afH[4], afL[4], bfH[4], bfL[4];
#pragma unroll
        for (int mt = 0; mt < 4; ++mt) {
            afH[mt] = *(const bf16x8s*)&AsH[wm + mt * 16 + ln][quad * 8];
            afL[mt] = *(const bf16x8s*)&AsL[wm + mt * 16 + ln][quad * 8];
        }
#pragma unroll
        for (int nt = 0; nt < 4; ++nt) {
            bfH[nt] = *(const bf16x8s*)&BsH[wn + nt * 16 + ln][quad * 8];
            bfL[nt] = *(const bf16x8s*)&BsL[wn + nt * 16 + ln][quad * 8];
        }
#pragma unroll
        for (int mt = 0; mt < 4; ++mt)
#pragma unroll
            for (int nt = 0; nt < 4; ++nt) {
                acc[mt][nt] = __builtin_amdgcn_mfma_f32_16x16x32_bf16(afH[mt], bfH[nt], acc[mt][nt], 0, 0, 0);
                acc[mt][nt] = __builtin_amdgcn_mfma_f32_16x16x32_bf16(afH[mt], bfL[nt], acc[mt][nt], 0, 0, 0);
                acc[mt][nt] = __builtin_amdgcn_mfma_f32_16x16x32_bf16(afL[mt], bfH[nt], acc[mt][nt], 0, 0, 0);
            }
    }

#pragma unroll
    for (int mt = 0; mt < 4; ++mt) {
        const int gr0 = row0 + wm + mt * 16 + quad * 4;
#pragma unroll
        for (int nt = 0; nt < 4; ++nt) {
            const int gc = col0 + wn + nt * 16 + ln;
            float bb = bias ? bias[gc] : 0.f;
#pragma unroll
            for (int r = 0; r < 4; ++r)
                C[(long)(gr0 + r) * ldc + gc] = acc[mt][nt][r] + bb;
        }
    }
}

// ============ wt_kernel: Wt[z][j][i] = exp(-L1(q_i,k_j)/4)*(j<=i) ============
__global__ __launch_bounds__(256) void wt_kernel(const float* __restrict__ qkv,
                                                 float* __restrict__ Wt)
{
    int z = blockIdx.y;
    int b = z >> 3, h = z & 7;
    int ti = blockIdx.x >> 2, tj = blockIdx.x & 3;
    int i0 = ti * 128, j0 = tj * 128;
    int t = threadIdx.x;
    long zo = (long)z * Ss * Ss;

    if (tj > ti) {   // fully masked: zero-fill
        float4 zz = make_float4(0.f, 0.f, 0.f, 0.f);
#pragma unroll
        for (int r = 0; r < 16; ++r) {
            int idx = r * 256 + t;
            int row = idx >> 5, col4 = idx & 31;
            *(float4*)&Wt[zo + (long)(j0 + row) * Ss + i0 + col4 * 4] = zz;
        }
        return;
    }

    int ia = (t & 15) * 4;
    int ja = (t >> 4) * 4;
    __shared__ float qs[32][128];
    __shared__ float ks[32][128];
    const float* qb = qkv + (long)b * Ss * (3 * DIM) + h * HD;
    const float* kb = qb + DIM;

    float acc[8][8] = {};

    for (int d0 = 0; d0 < 64; d0 += 32) {
        __syncthreads();
        int col = t & 127, dg = t >> 7;
#pragma unroll
        for (int e = 0; e < 4; ++e) {
            int d = dg * 16 + e * 4;
            float4 qv = *(const float4*)&qb[(long)(i0 + col) * (3 * DIM) + d0 + d];
            float4 kv = *(const float4*)&kb[(long)(j0 + col) * (3 * DIM) + d0 + d];
            qs[d+0][col] = qv.x; qs[d+1][col] = qv.y; qs[d+2][col] = qv.z; qs[d+3][col] = qv.w;
            ks[d+0][col] = kv.x; ks[d+1][col] = kv.y; ks[d+2][col] = kv.z; ks[d+3][col] = kv.w;
        }
        __syncthreads();
#pragma unroll
        for (int d = 0; d < 32; ++d) {
            float4 q0 = *(const float4*)&qs[d][ia];
            float4 q1 = *(const float4*)&qs[d][ia + 64];
            float4 k0 = *(const float4*)&ks[d][ja];
            float4 k1 = *(const float4*)&ks[d][ja + 64];
            float qv[8] = {q0.x,q0.y,q0.z,q0.w, q1.x,q1.y,q1.z,q1.w};
            float kv[8] = {k0.x,k0.y,k0.z,k0.w, k1.x,k1.y,k1.z,k1.w};
#pragma unroll
            for (int a = 0; a < 8; ++a)
#pragma unroll
                for (int c = 0; c < 8; ++c)
                    acc[a][c] += fabsf(qv[a] - kv[c]);
        }
    }

#pragma unroll
    for (int c = 0; c < 8; ++c) {
        int j = j0 + ja + (c & 3) + ((c >> 2) * 64);
        float o[8];
#pragma unroll
        for (int a = 0; a < 8; ++a) {
            int i = i0 + ia + (a & 3) + ((a >> 2) * 64);
            float e = expf(-acc[a][c] * 0.25f);
            o[a] = (j <= i) ? e : 0.0f;
        }
        *(float4*)&Wt[zo + (long)j * Ss + i0 + ia]      = make_float4(o[0],o[1],o[2],o[3]);
        *(float4*)&Wt[zo + (long)j * Ss + i0 + 64 + ia] = make_float4(o[4],o[5],o[6],o[7]);
    }
}

// ============ vt_pack: vT[z][d][k] = fp16(v[z][k][d]) ============
__global__ __launch_bounds__(256) void vt_pack(const float* __restrict__ qkv,
                                               _Float16* __restrict__ vT)
{
    int z = blockIdx.z;
    int b = z >> 3, h = z & 7;
    int kt = blockIdx.x * 32, dt = blockIdx.y * 32;
    int t = threadIdx.x;
    int d = t & 31, kr = t >> 5;
    __shared__ float sT[32][33];
#pragma unroll
    for (int p = 0; p < 4; ++p) {
        int kk = kr + p * 8;
        sT[kk][d] = qkv[(long)b * (Ss * 3 * DIM) + (long)(kt + kk) * (3 * DIM) + 2 * DIM + h * HD + dt + d];
    }
    __syncthreads();
#pragma unroll
    for (int p = 0; p < 4; ++p) {
        int dd = kr + p * 8;
        vT[(long)z * (HD * Ss) + (long)(dt + dd) * Ss + kt + d] = (_Float16)sT[d][dd];
    }
}

// ============ norms ============
__global__ __launch_bounds__(256) void normsA_k(const float* __restrict__ Wt,
                                                float* __restrict__ colsum,
                                                unsigned int* __restrict__ rowmaxb)
{
    int z = blockIdx.y;
    int r0 = blockIdx.x * 64;
    int t = threadIdx.x;
    const float* M = Wt + (long)z * Ss * Ss;
    float c0 = 0.f, c1 = 0.f;
    for (int r = 0; r < 64; ++r) {
        const float* row = M + (long)(r0 + r) * Ss;
        c0 += row[t];
        c1 += row[t + 256];
    }
    atomicAdd(&colsum[z * Ss + t], c0);
    atomicAdd(&colsum[z * Ss + t + 256], c1);
    int wave = t >> 6, lane = t & 63;
    float lmax = 0.f;
    for (int rr = 0; rr < 16; ++rr) {
        int row = r0 + wave * 16 + rr;
        const float* rp = M + (long)row * Ss;
        float s = 0.f;
#pragma unroll
        for (int c = 0; c < 8; ++c) s += rp[c * 64 + lane];
        for (int off = 32; off > 0; off >>= 1) s += __shfl_down(s, off);
        if (lane == 0) lmax = fmaxf(lmax, s);
    }
    if (lane == 0) atomicMax(&rowmaxb[z], __float_as_uint(lmax));
}

__global__ __launch_bounds__(512) void normsB_k(const float* __restrict__ colsum,
                                                const unsigned int* __restrict__ rowmaxb,
                                                float* __restrict__ nn,
                                                float* __restrict__ scale)
{
    int z = blockIdx.x;
    int t = threadIdx.x;
    __shared__ float sm[512];
    sm[t] = colsum[z * Ss + t];
    __syncthreads();
    for (int off = 256; off > 0; off >>= 1) {
        if (t < off) sm[t] = fmaxf(sm[t], sm[t + off]);
        __syncthreads();
    }
    if (t == 0) {
        float n1 = __uint_as_float(rowmaxb[z]);
        float v = n1 * sm[0];
        nn[z] = v;
        scale[z] = 1.0f / v;
    }
}

// ============ stats ============
__global__ __launch_bounds__(256) void stats2_k(const float* __restrict__ Wt,
                                                float* __restrict__ mu_out,
                                                float* __restrict__ inv_sig)
{
    int h = blockIdx.x;
    int wave = threadIdx.x >> 6, lane = threadIdx.x & 63;
    int j = blockIdx.y * 4 + wave;
    float s = 0.f, q = 0.f;
#pragma unroll
    for (int b = 0; b < 2; ++b) {
        const float* row = Wt + (((long)b * Hh + h) * Ss + j) * Ss;
#pragma unroll
        for (int c = 0; c < 2; ++c) {
            float4 v = *(const float4*)&row[lane * 4 + c * 256];
            s += v.x + v.y + v.z + v.w;
            q += v.x * v.x + v.y * v.y + v.z * v.z + v.w * v.w;
        }
    }
    for (int off = 32; off > 0; off >>= 1) {
        s += __shfl_down(s, off);
        q += __shfl_down(q, off);
    }
    if (lane == 0) {
        const float N = (float)(Bq * Ss);
        float mu = s / N;
        float var = (q - s * s / N) / (N - 1.0f);
        inv_sig[h * Ss + j] = 1.0f / sqrtf(var + 1e-5f);
        mu_out[h * Ss + j] = mu;
    }
}

// ============ prep: E_A = W-I, F_A = Wt*s-I, F_B = F^T (fp16) ============
__global__ __launch_bounds__(256) void prep_k(const float* __restrict__ Wt,
                                              const float* __restrict__ scale,
                                              _Float16* __restrict__ E_A,
                                              _Float16* __restrict__ F_A,
                                              _Float16* __restrict__ F_B)
{
    int z = blockIdx.z;
    long zo = (long)z * Ss * Ss;
    int ti = blockIdx.y * 32, tj = blockIdx.x * 32;
    int t = threadIdx.x;
    int c = t & 31, r0 = t >> 5;
    float s = scale[z];
    __shared__ float tb[32][33];
#pragma unroll
    for (int p = 0; p < 4; ++p) {
        int r = r0 + p * 8;
        long ia = zo + (long)(ti + r) * Ss + tj + c;
        float va = Wt[ia];
        float da = ((ti + r) == (tj + c)) ? 1.f : 0.f;
        F_A[ia] = (_Float16)(va * s - da);
        tb[r][c] = Wt[zo + (long)(tj + r) * Ss + ti + c];
    }
    __syncthreads();
#pragma unroll
    for (int p = 0; p < 4; ++p) {
        int r = r0 + p * 8;
        int gi = ti + r, gj = tj + c;
        float vb = tb[c][r];
        float dd = (gi == gj) ? 1.f : 0.f;
        long oa = zo + (long)gi * Ss + gj;
        E_A[oa] = (_Float16)(vb - dd);
        F_B[oa] = (_Float16)(vb * s - dd);
    }
}

// ============ NS GEMM fp16: P = A@B, R = sign*(A_c + V_c + P) ============
// tri: 0 full; 1 kend=row0+128 (A=E lower); 2 kend=min(row0,col0)+128 (A=E, B=F0 upper);
//      3 kbeg=row0 (A=F0 upper)
__global__ __launch_bounds__(256) void ns_gemm_k(
    const _Float16* __restrict__ Amat,
    const _Float16* __restrict__ Bmat,
    const _Float16* __restrict__ Vmat,
    _Float16* __restrict__ RA,
    _Float16* __restrict__ RB,
    float sign, int tri)
{
    const int z = blockIdx.z;
    const long zo = (long)z * Ss * Ss;
    const int row0 = blockIdx.y * 128, col0 = blockIdx.x * 128;
    const int kbeg = (tri == 3) ? row0 : 0;
    const int kend = (tri == 1) ? row0 + 128
                   : (tri == 2) ? ((row0 < col0 ? row0 : col0) + 128) : Ss;
    __shared__ _Float16 As[128][40];
    __shared__ _Float16 Bs[128][40];
    const int t = threadIdx.x;
    const int wave = t >> 6, lane = t & 63;
    const int ln = lane & 15, quad = lane >> 4;
    const int wm = (wave & 1) * 64, wn = (wave >> 1) * 64;

    f32x4 acc[4][4];
#pragma unroll
    for (int i = 0; i < 4; ++i)
#pragma unroll
        for (int j = 0; j < 4; ++j)
            acc[i][j] = (f32x4){0.f, 0.f, 0.f, 0.f};

    const int r2 = t >> 1, c2 = (t & 1) * 16;

    for (int k0 = kbeg; k0 < kend; k0 += 32) {
        __syncthreads();
        *(uint4*)&As[r2][c2]     = *(const uint4*)&Amat[zo + (long)(row0 + r2) * Ss + k0 + c2];
        *(uint4*)&As[r2][c2 + 8] = *(const uint4*)&Amat[zo + (long)(row0 + r2) * Ss + k0 + c2 + 8];
        *(uint4*)&Bs[r2][c2]     = *(const uint4*)&Bmat[zo + (long)(col0 + r2) * Ss + k0 + c2];
        *(uint4*)&Bs[r2][c2 + 8] = *(const uint4*)&Bmat[zo + (long)(col0 + r2) * Ss + k0 + c2 + 8];
        __syncthreads();

        f16x8 af[4], bf[4];
#pragma unroll
        for (int mt = 0; mt < 4; ++mt)
            af[mt] = *(const f16x8*)&As[wm + mt * 16 + ln][quad * 8];
#pragma unroll
        for (int nt = 0; nt < 4; ++nt)
            bf[nt] = *(const f16x8*)&Bs[wn + nt * 16 + ln][quad * 8];
#pragma unroll
        for (int mt = 0; mt < 4; ++mt)
#pragma unroll
            for (int nt = 0; nt < 4; ++nt)
                acc[mt][nt] = __builtin_amdgcn_mfma_f32_16x16x32_f16(af[mt], bf[nt], acc[mt][nt], 0, 0, 0);
    }

#pragma unroll
    for (int mt = 0; mt < 4; ++mt) {
        const int gr0 = row0 + wm + mt * 16 + quad * 4;
#pragma unroll
        for (int nt = 0; nt < 4; ++nt) {
            const int gc = col0 + wn + nt * 16 + ln;
            _Float16 rb[4] __attribute__((aligned(8)));
#pragma unroll
            for (int r = 0; r < 4; ++r) {
                const long gi = zo + (long)(gr0 + r) * Ss + gc;
                float a = (float)Amat[gi];
                float v = (float)Vmat[gi];
                _Float16 o = (_Float16)(sign * (a + v + acc[mt][nt][r]));
                RA[gi] = o;
                rb[r] = o;
            }
            *(uint2*)&RB[zo + (long)gc * Ss + gr0] = *(const uint2*)rb;
        }
    }
}

// ============ skinny_k<MODE>: 64x64 tile fp16 MFMA, fused epilogues ============
// MODE 0: ctx = (V + P)*nn[z]     A=F0 (kbeg=m0), V=v in qkv(ld 1536); out ctx + ctxT
// MODE 1: c2s = is[h,m]*(V + P)   A=F  (full),    V=ctx(ld 64);        out c2s + c2sT
// MODE 2: gat = V + P + neg[z,n]  A=E  (kend=m0+64), V=c2s(ld 64);     out gat[B,S,DIM]
template<int MODE>
__global__ __launch_bounds__(256) void skinny_k(
    const _Float16* __restrict__ Ap,
    const _Float16* __restrict__ Bp,
    const float* __restrict__ Vf,
    float* __restrict__ Cf,
    _Float16* __restrict__ CtP,
    const float* __restrict__ aux)
{
    const int z = blockIdx.y;
    const int b = z >> 3, h = z & 7;
    const int m0 = blockIdx.x * 64;
    const long zA = (long)z * Ss * Ss;
    const long zB = (long)z * HD * Ss;
    const int kbeg = (MODE == 0) ? m0 : 0;
    const int kend = (MODE == 2) ? m0 + 64 : Ss;

    __shared__ _Float16 As[64][40];
    __shared__ _Float16 Bs[64][40];
    const int t = threadIdx.x;
    const int wave = t >> 6, lane = t & 63;
    const int ln = lane & 15, quad = lane >> 4;
    const int r4 = t >> 2, c4 = (t & 3) * 8;

    f32x4 acc[4];
#pragma unroll
    for (int i = 0; i < 4; ++i) acc[i] = (f32x4){0.f, 0.f, 0.f, 0.f};

    for (int k0 = kbeg; k0 < kend; k0 += 32) {
        __syncthreads();
        *(uint4*)&As[r4][c4] = *(const uint4*)&Ap[zA + (long)(m0 + r4) * Ss + k0 + c4];
        *(uint4*)&Bs[r4][c4] = *(const uint4*)&Bp[zB + (long)r4 * Ss + k0 + c4];
        __syncthreads();

        f16x8 af = *(const f16x8*)&As[wave * 16 + ln][quad * 8];
#pragma unroll
        for (int nt = 0; nt < 4; ++nt) {
            f16x8 bf = *(const f16x8*)&Bs[nt * 16 + ln][quad * 8];
            acc[nt] = __builtin_amdgcn_mfma_f32_16x16x32_f16(af, bf, acc[nt], 0, 0, 0);
        }
    }

    const int gr = wave * 16 + quad * 4;
#pragma unroll
    for (int nt = 0; nt < 4; ++nt) {
        const int col = nt * 16 + ln;
        _Float16 rb[4] __attribute__((aligned(8)));
#pragma unroll
        for (int r = 0; r < 4; ++r) {
            const int m = m0 + gr + r;
            float vv, val;
            if (MODE == 0) {
                vv = Vf[(long)b * (Ss * 3 * DIM) + (long)m * (3 * DIM) + h * HD + col];
                val = (vv + acc[nt][r]) * aux[z];
            } else if (MODE == 1) {
                vv = Vf[zB + (long)m * HD + col];
                val = aux[h * Ss + m] * (vv + acc[nt][r]);
            } else {
                vv = Vf[zB + (long)m * HD + col];
                val = vv + acc[nt][r] + aux[z * HD + col];
            }
            if (MODE < 2) {
                Cf[zB + (long)m * HD + col] = val;
                rb[r] = (_Float16)val;
            } else {
                Cf[(long)b * (Ss * DIM) + (long)m * DIM + h * HD + col] = val;
            }
        }
        if (MODE < 2)
            *(uint2*)&CtP[zB + (long)col * Ss + m0 + gr] = *(const uint2*)rb;
    }
}

// ============ negoff ============
__global__ __launch_bounds__(256) void negoff_k(const float* __restrict__ mu,
                                                const float* __restrict__ c2s,
                                                float* __restrict__ negoffs)
{
    int z = blockIdx.x;
    int h = z & 7;
    int t = threadIdx.x;
    int part = t >> 6, d = t & 63;
    float s = 0.f;
    for (int j = part * 128; j < part * 128 + 128; ++j)
        s += mu[h * Ss + j] * c2s[(long)z * (Ss * HD) + (long)j * HD + d];
    __shared__ float red[4][64];
    red[part][d] = s;
    __syncthreads();
    if (t < 64)
        negoffs[z * HD + t] = -(red[0][t] + red[1][t] + red[2][t] + red[3][t]);
}

extern "C" void kernel_launch(void* const* d_in, const int* in_sizes, int n_in,
                              void* d_out, int out_size, void* d_ws, size_t ws_size,
                              hipStream_t stream)
{
    const float* x      = (const float*)d_in[0];
    const float* qkv_w  = (const float*)d_in[1];
    const float* qkv_b  = (const float*)d_in[2];
    const float* proj_w = (const float*)d_in[3];
    const float* proj_b = (const float*)d_in[4];
    float* out = (float*)d_out;
    float* ws  = (float*)d_ws;

    const long SS = (long)Ss * Ss;          // 262144
    const long BH = (long)Bq * Hh;          // 16
    const long CT = (long)HD * Ss;          // 32768

    float* qkv  = ws;                                    // 1,572,864 f
    float* Wt   = qkv + (long)Bq * Ss * 3 * DIM;         // 4,194,304 f
    float* ctx  = Wt + BH * SS;                          //   524,288 f
    _Float16* ctxT = (_Float16*)(ctx + BH * CT);         //   524,288 h (= 262,144 f)
    _Float16* vT   = ctxT + BH * CT;                     //   524,288 h
    _Float16* E_A  = vT + BH * CT;                       // 4,194,304 h each
    _Float16* F_A  = E_A + BH * SS;
    _Float16* F_B  = F_A + BH * SS;
    _Float16* G_B  = F_B + BH * SS;
    float* colsum = (float*)(G_B + BH * SS);             // 8192 f
    unsigned int* rowmaxb = (unsigned int*)(colsum + Hh * 2 * Ss);  // 16 u
    float* nn      = (float*)(rowmaxb + 16);
    float* scale   = nn + 16;
    float* mu      = scale + 16;                         // 4096
    float* inv_sig = mu + Hh * Ss;                       // 4096
    float* negoffs = inv_sig + Hh * Ss;                  // 1024
    // overlays
    _Float16* G_A = (_Float16*)Wt;                       // Wt dead after prep (8.4 MB of 16.8)
    float* gat = Wt + 2097152;                           // upper half of Wt region
    float* c2s = qkv;                                    // qkv dead after skinny<0>
    _Float16* c2sT = (_Float16*)(qkv + BH * CT);

    dim3 blk(256);

    // 1. qkv = x @ qkv_w^T + qkv_b
    mm_k<<<dim3(1536 / 128, 1024 / 128), blk, 0, stream>>>(x, qkv_w, qkv_b, qkv, DIM, 3 * DIM);

    // 2. Wt
    wt_kernel<<<dim3(16, 16), blk, 0, stream>>>(qkv, Wt);

    // 3. vT fp16
    vt_pack<<<dim3(16, 2, 16), blk, 0, stream>>>(qkv, vT);

    // 4. norms
    hipMemsetAsync(colsum, 0, (Hh * 2 * Ss + 16) * sizeof(float), stream);
    normsA_k<<<dim3(8, 16), blk, 0, stream>>>(Wt, colsum, rowmaxb);
    normsB_k<<<dim3(16), dim3(512), 0, stream>>>(colsum, rowmaxb, nn, scale);

    // 5. stats
    stats2_k<<<dim3(Hh, 128), blk, 0, stream>>>(Wt, mu, inv_sig);

    // 6. E, F0 fp16
    prep_k<<<dim3(16, 16, 16), blk, 0, stream>>>(Wt, scale, E_A, F_A, F_B);

    // 7. ctx = (F0@v + v)*nn   (skinny MODE 0, kbeg=m0: F0 upper-tri)
    skinny_k<0><<<dim3(8, 16), blk, 0, stream>>>(F_A, vT, qkv + 2 * DIM, ctx, ctxT, nn);

    // 8. Newton-Schulz fp16: G = -(E+F+E@F); F' = F+G+F@G
    _Float16 *fA = F_A, *fB = F_B, *gA = G_A, *gB = G_B;
    for (int it = 0; it < 5; ++it) {
        ns_gemm_k<<<dim3(4, 4, 16), blk, 0, stream>>>(E_A, fB, fA, gA, gB, -1.0f, it == 0 ? 2 : 1);
        ns_gemm_k<<<dim3(4, 4, 16), blk, 0, stream>>>(fA, gB, gA, gA, fB, 1.0f, it == 0 ? 3 : 0);
        _Float16* tmp = fA; fA = gA; gA = tmp;
    }

    // 9. c2s = inv_sig * (ctx + F@ctx)   (skinny MODE 1)
    skinny_k<1><<<dim3(8, 16), blk, 0, stream>>>(fA, ctxT, ctx, c2s, c2sT, inv_sig);

    // 10. negoffs
    negoff_k<<<dim3(16), blk, 0, stream>>>(mu, c2s, negoffs);

    // 11. gat = c2s + E@c2s + negoffs   (skinny MODE 2, kend=m0+64: E lower-tri)
    skinny_k<2><<<dim3(8, 16), blk, 0, stream>>>(E_A, c2sT, c2s, gat, nullptr, negoffs);

    // 12. out = gat @ proj_w^T + proj_b
    mm_k<<<dim3(512 / 128, 1024 / 128), blk, 0, stream>>>(gat, proj_w, proj_b, out, DIM, DIM);
}